// Round 10
// baseline (70.865 us; speedup 1.0000x reference)
//
#include <hip/hip_runtime.h>

// Item-major segmented scan. seg is sorted, so block b owns items
// [b*CHUNK, (b+1)*CHUNK): ~5 whole sessions. Rows are read FULLY and
// coalesced (512 B bursts); per-session accumulate in registers, 8->1 LDS
// reduce, scale by 1/len; interior sessions plain-store, boundary sessions
// unsafeAtomicAdd (pre-scaled) onto zeroed out. Each ids[j] touched once.

constexpr int D = 128;
constexpr int CHUNK = 256;

typedef float f32x4 __attribute__((ext_vector_type(4)));

// prep: zero out[] and build starts[] via diff-scan of sorted seg.
__global__ __launch_bounds__(256)
void prep_kernel(const int* __restrict__ seg, int total, int nsess,
                 int* __restrict__ starts, float* __restrict__ out) {
    const int j = blockIdx.x * 256 + threadIdx.x;
    const int zn = nsess * (D / 4);              // out as float4 count
    if (j < zn) {
        f32x4 z = {0.f, 0.f, 0.f, 0.f};
        reinterpret_cast<f32x4*>(out)[j] = z;
    }
    if (j < total) {
        const int cur  = seg[j];
        const int prev = (j == 0) ? -1 : seg[j - 1];
        for (int s = prev + 1; s <= cur; ++s) starts[s] = j;   // starts[0]=0
        if (j == total - 1) {
            for (int s = cur + 1; s <= nsess; ++s) starts[s] = total;
        }
    }
}

// Block = 256 threads = 8 item-slots x 32 dim-quads (float4).
__global__ __launch_bounds__(256)
void seg_sum_chunk(const float* __restrict__ emb,
                   const int* __restrict__ ids,
                   const int* __restrict__ seg,
                   const int* __restrict__ starts,
                   float* __restrict__ out, int total) {
    __shared__ int   lids[CHUNK];
    __shared__ f32x4 red[8][32];

    const int j0 = blockIdx.x * CHUNK;
    const int j1 = (j0 + CHUNK < total) ? j0 + CHUNK : total;

    if (j0 + (int)threadIdx.x < j1)
        lids[threadIdx.x] = ids[j0 + threadIdx.x];

    const int s0 = seg[j0];          // block-uniform session range
    const int s1 = seg[j1 - 1];
    __syncthreads();

    const int islot = threadIdx.x >> 5;   // 0..7 item slots
    const int dq    = threadIdx.x & 31;   // float4 quad within the row

    for (int s = s0; s <= s1; ++s) {
        const int sa = starts[s];
        const int sb = starts[s + 1];
        const int a = (sa > j0) ? sa : j0;
        const int b = (sb < j1) ? sb : j1;

        float ax = 0.f, ay = 0.f, az = 0.f, aw = 0.f;
        for (int j = a + islot; j < b; j += 8) {
            const f32x4 v = reinterpret_cast<const f32x4*>(
                emb + (size_t)lids[j - j0] * D)[dq];
            ax += v.x; ay += v.y; az += v.z; aw += v.w;
        }
        f32x4 acc = {ax, ay, az, aw};
        red[islot][dq] = acc;
        __syncthreads();

        if (threadIdx.x < 32) {
            f32x4 sum = red[0][dq];
            #pragma unroll
            for (int k = 1; k < 8; ++k) {
                const f32x4 v = red[k][dq];
                sum.x += v.x; sum.y += v.y; sum.z += v.z; sum.w += v.w;
            }
            const int len = sb - sa;
            const float inv = (len > 0) ? 1.0f / (float)len : 0.0f;
            sum.x *= inv; sum.y *= inv; sum.z *= inv; sum.w *= inv;

            float* dst = out + (size_t)s * D + dq * 4;
            if (sa >= j0 && sb <= j1) {
                *reinterpret_cast<f32x4*>(dst) = sum;   // interior: exclusive
            } else {                                    // boundary: pre-scaled add
                unsafeAtomicAdd(dst + 0, sum.x);
                unsafeAtomicAdd(dst + 1, sum.y);
                unsafeAtomicAdd(dst + 2, sum.z);
                unsafeAtomicAdd(dst + 3, sum.w);
            }
        }
        __syncthreads();
    }
}

extern "C" void kernel_launch(void* const* d_in, const int* in_sizes, int n_in,
                              void* d_out, int out_size, void* d_ws, size_t ws_size,
                              hipStream_t stream) {
    const float* emb = (const float*)d_in[0];
    const int*   ids = (const int*)d_in[1];
    const int*   seg = (const int*)d_in[2];
    float*       out = (float*)d_out;

    const int total = in_sizes[1];        // TOTAL_ITEMS
    const int nsess = out_size / D;       // N_SESSIONS

    int* starts = (int*)d_ws;             // (nsess + 1) ints

    {
        const int zn = nsess * (D / 4);
        const int work = (total > zn) ? total : zn;
        const int blocks = (work + 255) / 256;
        prep_kernel<<<blocks, 256, 0, stream>>>(seg, total, nsess, starts, out);
    }
    {
        const int blocks = (total + CHUNK - 1) / CHUNK;
        seg_sum_chunk<<<blocks, 256, 0, stream>>>(emb, ids, seg, starts, out, total);
    }
}

// Round 11
// 54.322 us; speedup vs baseline: 1.3045x; 1.3045x over previous
//
#include <hip/hip_runtime.h>
#include <hip/hip_fp16.h>

// Segment-mean of gathered embeddings.
// Prep (one fused kernel): starts[] diff-scan + repack f32 -> fp16 in
//   4 slices of 32 dims: emb2[g][item][32] halves. Granule per (item,slice)
//   = 64 B (one L2 line); slice = 6.4 MB (partially L2-resident per XCD).
// Gather: thread = (session, dl 0..7); reads 8 B (dims 4dl..4dl+3) per item;
//   8-way unroll -> 64 granules in flight per wave. g = blockIdx%4 keeps the
//   slice<->XCD affinity (round-robin dispatch). ids staged in LDS as
//   prescaled byte offsets. No cross-lane ops.

constexpr int D = 128;
constexpr int IDS_CAP = 4096;     // 16 KB LDS; 32 sessions avg ~1600 ids

typedef float f32x2 __attribute__((ext_vector_type(2)));
typedef float f32x4 __attribute__((ext_vector_type(4)));
typedef unsigned int u32x2 __attribute__((ext_vector_type(2)));

// -------- fused prep: blocks [0, repack_blocks) repack, rest diff-scan -----
__global__ __launch_bounds__(256)
void prep_kernel(const float* __restrict__ emb, __half* __restrict__ emb2,
                 const int* __restrict__ seg, int* __restrict__ starts,
                 int nitems, int total, int nsess, int repack_blocks) {
    if ((int)blockIdx.x < repack_blocks) {
        // repack: one wave per item; lane covers dims 2*lane, 2*lane+1.
        const int item = blockIdx.x * 4 + (threadIdx.x >> 6);
        if (item >= nitems) return;
        const int lane = threadIdx.x & 63;
        const f32x2 v = __builtin_nontemporal_load(
            reinterpret_cast<const f32x2*>(emb + (size_t)item * D) + lane);
        const __half2 h = __floats2half2_rn(v.x, v.y);
        const int g = lane >> 4;                   // 32-dim slice 0..3
        const int o = lane & 15;                   // half2 slot within slice
        __half2* dst = reinterpret_cast<__half2*>(
            emb2 + (size_t)g * nitems * 32 + (size_t)item * 32);
        dst[o] = h;
    } else {
        const int j = ((int)blockIdx.x - repack_blocks) * 256 + threadIdx.x;
        if (j >= total) return;
        const int cur  = seg[j];
        const int prev = (j == 0) ? -1 : seg[j - 1];
        for (int s = prev + 1; s <= cur; ++s) starts[s] = j;
        if (j == total - 1) {
            for (int s = cur + 1; s <= nsess; ++s) starts[s] = total;
        }
    }
}

// Block = 32 sessions x 8 dl, slice g = blockIdx%4.
__global__ __launch_bounds__(256)
void gather_mean_g4(const __half* __restrict__ emb2,
                    const int* __restrict__ ids,
                    const int* __restrict__ starts,
                    float* __restrict__ out,
                    int nitems, int nsess) {
    __shared__ int lds_off[IDS_CAP];

    const int g    = blockIdx.x & 3;                          // XCD-stable slice
    const int s0   = (blockIdx.x >> 2) * 32;
    const int sidx = s0 + (threadIdx.x >> 3);
    const int dl   = threadIdx.x & 7;   // dims g*32 + 4*dl .. +3

    const int sEnd  = (s0 + 32 < nsess) ? s0 + 32 : nsess;
    const int base0 = starts[s0];
    const int range = starts[sEnd] - base0;
    const bool use_lds = (range <= IDS_CAP);

    if (use_lds) {
        for (int t = threadIdx.x; t < range; t += 256)
            lds_off[t] = ids[base0 + t] << 6;     // prescaled byte offset
    }
    __syncthreads();

    if (sidx >= nsess) return;

    const int beg = starts[sidx];
    const int len = starts[sidx + 1] - beg;

    const char* pbase = reinterpret_cast<const char*>(emb2)
                      + (size_t)g * nitems * 64 + dl * 8;

    float a0 = 0.f, a1 = 0.f, a2 = 0.f, a3 = 0.f;

    if (use_lds) {
        const int* offp = lds_off + (beg - base0);
        int j = 0;
        for (; j + 8 <= len; j += 8) {
            int off[8];
            #pragma unroll
            for (int k = 0; k < 8; ++k) off[k] = offp[j + k];
            u32x2 r[8];
            #pragma unroll
            for (int k = 0; k < 8; ++k)
                r[k] = *reinterpret_cast<const u32x2*>(pbase + (size_t)off[k]);
            #pragma unroll
            for (int k = 0; k < 8; ++k) {
                unsigned lo = r[k].x, hi = r[k].y;
                const float2 f0 = __half22float2(*reinterpret_cast<const __half2*>(&lo));
                const float2 f1 = __half22float2(*reinterpret_cast<const __half2*>(&hi));
                a0 += f0.x; a1 += f0.y; a2 += f1.x; a3 += f1.y;
            }
        }
        for (; j < len; ++j) {
            const u32x2 r = *reinterpret_cast<const u32x2*>(pbase + (size_t)offp[j]);
            unsigned lo = r.x, hi = r.y;
            const float2 f0 = __half22float2(*reinterpret_cast<const __half2*>(&lo));
            const float2 f1 = __half22float2(*reinterpret_cast<const __half2*>(&hi));
            a0 += f0.x; a1 += f0.y; a2 += f1.x; a3 += f1.y;
        }
    } else {                                   // overflow fallback (rare)
        const int* idp = ids + beg;
        for (int j = 0; j < len; ++j) {
            const u32x2 r = *reinterpret_cast<const u32x2*>(
                pbase + ((size_t)idp[j] << 6));
            unsigned lo = r.x, hi = r.y;
            const float2 f0 = __half22float2(*reinterpret_cast<const __half2*>(&lo));
            const float2 f1 = __half22float2(*reinterpret_cast<const __half2*>(&hi));
            a0 += f0.x; a1 += f0.y; a2 += f1.x; a3 += f1.y;
        }
    }

    const float inv = (len > 0) ? 1.0f / (float)len : 0.0f;
    f32x4 o = {a0 * inv, a1 * inv, a2 * inv, a3 * inv};
    *reinterpret_cast<f32x4*>(out + (size_t)sidx * D + g * 32 + dl * 4) = o;
}

// ---------------- fallback (ws too small): round-2 direct f32 gather --------
__global__ void find_starts_diff(const int* __restrict__ seg, int total,
                                 int nsess, int* __restrict__ starts) {
    int j = blockIdx.x * blockDim.x + threadIdx.x;
    if (j >= total) return;
    const int cur  = seg[j];
    const int prev = (j == 0) ? -1 : seg[j - 1];
    for (int s = prev + 1; s <= cur; ++s) starts[s] = j;
    if (j == total - 1) {
        for (int s = cur + 1; s <= nsess; ++s) starts[s] = total;
    }
}

__global__ __launch_bounds__(256)
void seg_mean_kernel(const float* __restrict__ emb,
                     const int* __restrict__ ids,
                     const int* __restrict__ starts,
                     float* __restrict__ out, int nsess) {
    const int tid  = threadIdx.x;
    const int s    = blockIdx.x * 4 + (tid >> 6);
    if (s >= nsess) return;
    const int lane = tid & 63;
    const int gq   = lane >> 5;
    const int l32  = lane & 31;

    const int beg = starts[s];
    const int end = starts[s + 1];

    float4 acc = make_float4(0.f, 0.f, 0.f, 0.f);
    for (int j = beg + gq; j < end; j += 2) {
        const int id = ids[j];
        const float4 v = reinterpret_cast<const float4*>(emb + (size_t)id * D)[l32];
        acc.x += v.x; acc.y += v.y; acc.z += v.z; acc.w += v.w;
    }
    acc.x += __shfl_down(acc.x, 32);
    acc.y += __shfl_down(acc.y, 32);
    acc.z += __shfl_down(acc.z, 32);
    acc.w += __shfl_down(acc.w, 32);
    if (lane < 32) {
        const int cnt = end - beg;
        const float inv = (cnt > 0) ? 1.0f / (float)cnt : 0.0f;
        const float4 o = make_float4(acc.x * inv, acc.y * inv,
                                     acc.z * inv, acc.w * inv);
        reinterpret_cast<float4*>(out + (size_t)s * D)[l32] = o;
    }
}

extern "C" void kernel_launch(void* const* d_in, const int* in_sizes, int n_in,
                              void* d_out, int out_size, void* d_ws, size_t ws_size,
                              hipStream_t stream) {
    const float* emb = (const float*)d_in[0];
    const int*   ids = (const int*)d_in[1];
    const int*   seg = (const int*)d_in[2];
    float*       out = (float*)d_out;

    const int total  = in_sizes[1];        // TOTAL_ITEMS
    const int nsess  = out_size / D;       // N_SESSIONS
    const int nitems = in_sizes[0] / D;    // N_ITEMS

    // FULL fp16 table: nitems * 128 dims * 2 B = 25.6 MB (4 slices x 6.4 MB)
    const size_t emb2_bytes = (size_t)nitems * D * 2;
    const size_t emb2_pad   = (emb2_bytes + 255) & ~(size_t)255;
    const size_t need       = emb2_pad + (size_t)(nsess + 1) * 4;

    if (ws_size >= need) {
        __half* emb2   = (__half*)d_ws;
        int*    starts = (int*)((char*)d_ws + emb2_pad);

        {
            const int repack_blocks = (nitems + 3) / 4;
            const int starts_blocks = (total + 255) / 256;
            prep_kernel<<<repack_blocks + starts_blocks, 256, 0, stream>>>(
                emb, emb2, seg, starts, nitems, total, nsess, repack_blocks);
        }
        {
            const int sgroups = (nsess + 31) / 32;
            gather_mean_g4<<<sgroups * 4, 256, 0, stream>>>(emb2, ids, starts,
                                                            out, nitems, nsess);
        }
    } else {
        int* starts = (int*)d_ws;
        {
            const int threads = 256;
            const int blocks = (total + threads - 1) / threads;
            find_starts_diff<<<blocks, threads, 0, stream>>>(seg, total, nsess, starts);
        }
        {
            const int blocks = (nsess + 3) / 4;
            seg_mean_kernel<<<blocks, 256, 0, stream>>>(emb, ids, starts, out, nsess);
        }
    }
}